// Round 5
// baseline (109.037 us; speedup 1.0000x reference)
//
#include <hip/hip_runtime.h>

// ShiftLocalAttention2d: 7x7 neighborhood attention, B=4, C=256 (8 heads x 32),
// H=W=48. fp32 in/out, fp32 accumulate. K/V staged in LDS as f16.
//
// R5: latency attack. CSTR=36 (72B/px, b64 reads) -> LDS 38.2KB -> 4 blocks/CU;
// __launch_bounds__(384,6) -> VGPR<=85 -> 24 waves/CU (was 16, VGPR-capped).
// Inner loop phase-split per row: 8 K-reads + 8 independent score chains + exp,
// then 8 V-reads + PV. Shorter critical path, lower reg pressure, more MLP.

#define H_IMG 48
#define W_IMG 48
#define DHEAD 32
#define NH    8
#define RAD   3
#define TW    16
#define TH    6
#define NPART 4
#define CPL   8                      // channels per lane
#define HALO_W  (TW + 2*RAD)         // 22
#define HALO_H  (TH + 2*RAD)         // 12
#define HALO_PX (HALO_W * HALO_H)    // 264
#define CSTR    36                   // shorts per pixel (72B; 8B-aligned b64s)
#define PLANE   (H_IMG * W_IMG)      // 2304
#define NTHREADS (NPART * TW * TH)   // 384

typedef _Float16 half_t;
typedef half_t half2_t __attribute__((ext_vector_type(2)));

// in-quad butterfly adds via DPP quad_perm (VALU pipe, not LDS)
__device__ __forceinline__ float dppadd1(float x) {   // + lane^1
  int y = __builtin_amdgcn_update_dpp(0, __float_as_int(x), 0xB1, 0xF, 0xF, true);
  return x + __int_as_float(y);
}
__device__ __forceinline__ float dppadd2(float x) {   // + lane^2
  int y = __builtin_amdgcn_update_dpp(0, __float_as_int(x), 0x4E, 0xF, 0xF, true);
  return x + __int_as_float(y);
}

__global__ __launch_bounds__(NTHREADS, 6)
void natten_f32_kernel(const float* __restrict__ q,
                       const float* __restrict__ k,
                       const float* __restrict__ v,
                       float* __restrict__ out) {
  __shared__ __align__(16) unsigned short kl[(HALO_PX + 1) * CSTR];
  __shared__ __align__(16) unsigned short vl[(HALO_PX + 1) * CSTR];

  const int part = threadIdx.x;           // 0..3  (channel quarter)
  const int qx   = threadIdx.y;           // 0..15
  const int qy   = threadIdx.z;           // 0..5  (wave index)
  const int tid  = part + NPART * qx + NPART * TW * qy;
  const int x0   = blockIdx.x * TW;
  const int y0   = blockIdx.y * TH;
  const size_t cbase = (size_t)blockIdx.z * DHEAD * PLANE;

  // ---- Stage K/V halo as packed f16: task = (pixel, 8-channel chunk) ----
  for (int i = tid; i < HALO_PX * 4; i += NTHREADS) {
    const int pix = i >> 2, chunk = i & 3;
    const int hy = pix / HALO_W;
    const int hx = pix - hy * HALO_W;
    const int gy = y0 - RAD + hy;
    const int gx = x0 - RAD + hx;
    union { half2_t h2[4]; uint2 u[2]; } kk, vv;
    kk.u[0] = make_uint2(0, 0); kk.u[1] = make_uint2(0, 0);
    vv.u[0] = make_uint2(0, 0); vv.u[1] = make_uint2(0, 0);
    if ((unsigned)gy < (unsigned)H_IMG && (unsigned)gx < (unsigned)W_IMG) {
      const size_t g = cbase + (size_t)(chunk * CPL) * PLANE + (size_t)gy * W_IMG + gx;
      const float* kb = k + g;
      const float* vb = v + g;
#pragma unroll
      for (int j = 0; j < 4; ++j) {
        half2_t a, b;
        a.x = (half_t)kb[(2 * j) * PLANE];  a.y = (half_t)kb[(2 * j + 1) * PLANE];
        b.x = (half_t)vb[(2 * j) * PLANE];  b.y = (half_t)vb[(2 * j + 1) * PLANE];
        kk.h2[j] = a;  vv.h2[j] = b;
      }
    }
    const int off = pix * CSTR + chunk * CPL;
    *(uint2*)&kl[off]     = kk.u[0];
    *(uint2*)&kl[off + 4] = kk.u[1];
    *(uint2*)&vl[off]     = vv.u[0];
    *(uint2*)&vl[off + 4] = vv.u[1];
  }
  if (tid < CSTR) {                       // zero the pad pixel (rx=7 reads it)
    kl[HALO_PX * CSTR + tid] = 0;
    vl[HALO_PX * CSTR + tid] = 0;
  }

  // ---- This lane's 8 query channels, pre-scaled, packed f16x2 ----
  const int gqx = x0 + qx, gqy = y0 + qy;
  const float S = 0.17677669529663687f;    // 1/sqrt(32)
  const size_t qoff = cbase + (size_t)gqy * W_IMG + gqx;
  half2_t qp[4];
#pragma unroll
  for (int j = 0; j < 4; ++j) {
    qp[j].x = (half_t)(q[qoff + (size_t)(part * CPL + 2 * j) * PLANE] * S);
    qp[j].y = (half_t)(q[qoff + (size_t)(part * CPL + 2 * j + 1) * PLANE] * S);
  }

  // ---- per-lane column validity mask (row-invariant); bit7 = 0 ----
  unsigned colmask = 0;
#pragma unroll
  for (int rx = 0; rx < 7; ++rx) {
    const int gx = gqx + rx - RAD;
    if ((unsigned)gx < (unsigned)W_IMG) colmask |= (1u << rx);
  }

  __syncthreads();

  float den = 0.0f;
  float o[CPL];
#pragma unroll
  for (int j = 0; j < CPL; ++j) o[j] = 0.0f;

  for (int ry = 0; ry < 2 * RAD + 1; ++ry) {
    const int gy = gqy + ry - RAD;
    const unsigned mrow = ((unsigned)gy < (unsigned)H_IMG) ? colmask : 0u;
    const int base = ((qy + ry) * HALO_W + qx) * CSTR + part * CPL;
    const unsigned short* kb = &kl[base];
    const unsigned short* vb = &vl[base];

    // -- phase A: 8 independent score chains --
    float p[8];
#pragma unroll
    for (int rx = 0; rx < 8; ++rx) {       // rx=7 is padding (mask bit 0)
      union { uint2 u; half2_t h[2]; } k0, k1;
      k0.u = *(const uint2*)(kb + rx * CSTR);
      k1.u = *(const uint2*)(kb + rx * CSTR + 4);
      float a0 = __builtin_amdgcn_fdot2(qp[0], k0.h[0], 0.0f, false);
      a0 = __builtin_amdgcn_fdot2(qp[1], k0.h[1], a0, false);
      float a1 = __builtin_amdgcn_fdot2(qp[2], k1.h[0], 0.0f, false);
      a1 = __builtin_amdgcn_fdot2(qp[3], k1.h[1], a1, false);
      float acc = a0 + a1;
      acc = dppadd1(acc);                  // parts {0,1},{2,3}
      acc = dppadd2(acc);                  // full 32-ch dot in all 4 part-lanes
      p[rx] = (mrow & (1u << rx)) ? __expf(acc) : 0.0f;
    }
    den += ((p[0] + p[1]) + (p[2] + p[3])) + ((p[4] + p[5]) + (p[6] + p[7]));

    // -- phase B: PV accumulate --
#pragma unroll
    for (int rx = 0; rx < 8; ++rx) {
      union { uint2 u; half2_t h[2]; } v0, v1;
      v0.u = *(const uint2*)(vb + rx * CSTR);
      v1.u = *(const uint2*)(vb + rx * CSTR + 4);
      const float pw = p[rx];
      o[0] += pw * (float)v0.h[0].x;  o[1] += pw * (float)v0.h[0].y;
      o[2] += pw * (float)v0.h[1].x;  o[3] += pw * (float)v0.h[1].y;
      o[4] += pw * (float)v1.h[0].x;  o[5] += pw * (float)v1.h[0].y;
      o[6] += pw * (float)v1.h[1].x;  o[7] += pw * (float)v1.h[1].y;
    }
  }

  const float rden = 1.0f / den;           // den >= exp(center score) > 0
#pragma unroll
  for (int j = 0; j < CPL; ++j)
    out[qoff + (size_t)(part * CPL + j) * PLANE] = o[j] * rden;
}

extern "C" void kernel_launch(void* const* d_in, const int* in_sizes, int n_in,
                              void* d_out, int out_size, void* d_ws, size_t ws_size,
                              hipStream_t stream) {
  const float* q = (const float*)d_in[0];
  const float* k = (const float*)d_in[1];
  const float* v = (const float*)d_in[2];
  float* out = (float*)d_out;

  dim3 grid(W_IMG / TW, H_IMG / TH, 4 * NH);   // (3, 8, 32) = 768 blocks
  dim3 block(NPART, TW, TH);                    // 384 threads = 6 waves
  hipLaunchKernelGGL(natten_f32_kernel, grid, block, 0, stream, q, k, v, out);
}